// Round 1
// baseline (191.182 us; speedup 1.0000x reference)
//
#include <hip/hip_runtime.h>

#define NBOX 8192
#define BT 1024
#define MAXDET 100
#define SCORE_T 0.05f
#define NMS_T 0.5f

__device__ __forceinline__ float iou_fn(float x1, float y1, float x2, float y2, float area,
                                        float bx1, float by1, float bx2, float by2, float barea) {
    float iw = fminf(x2, bx2) - fmaxf(x1, bx1);
    float ih = fminf(y2, by2) - fmaxf(y1, by1);
    iw = fmaxf(iw, 0.0f);
    ih = fmaxf(ih, 0.0f);
    float inter = iw * ih;
    return inter / fmaxf(area + barea - inter, 1e-8f);
}

__global__ __launch_bounds__(BT) void filterdet_kernel(
    const float* __restrict__ boxes, const float* __restrict__ dims,
    const float* __restrict__ cls, float* __restrict__ out) {
    __shared__ float s_sc[NBOX];
    __shared__ unsigned short s_ix[NBOX];
    __shared__ float s_kx1[MAXDET], s_ky1[MAXDET], s_kx2[MAXDET], s_ky2[MAXDET];
    __shared__ float s_karea[MAXDET], s_kscore[MAXDET];
    __shared__ int s_ksel[MAXDET];
    __shared__ int s_kc;

    const int tid = threadIdx.x;

    // ---- Phase 1: per-box score = max over folded 4 classes ----
    for (int i = tid; i < NBOX; i += BT) {
        const float4 c0 = *reinterpret_cast<const float4*>(cls + i * 8);
        const float4 c1 = *reinterpret_cast<const float4*>(cls + i * 8 + 4);
        float m0 = fmaxf(c0.x, c1.x);
        float m1 = fmaxf(c0.y, c1.y);
        float m2 = fmaxf(c0.z, c1.z);
        float m3 = fmaxf(c0.w, c1.w);
        s_sc[i] = fmaxf(fmaxf(m0, m1), fmaxf(m2, m3));
        s_ix[i] = (unsigned short)i;
    }

    // ---- Phase 2: bitonic sort descending by (score, idx asc tiebreak) ----
    for (int kk = 2; kk <= NBOX; kk <<= 1) {
        for (int jj = kk >> 1; jj > 0; jj >>= 1) {
            __syncthreads();
            for (int i = tid; i < NBOX; i += BT) {
                int l = i ^ jj;
                if (l > i) {
                    float a = s_sc[i], b = s_sc[l];
                    unsigned short ai = s_ix[i], bi = s_ix[l];
                    bool ib4l = (a > b) || (a == b && ai < bi);  // "i belongs before l" in desc order
                    bool dirDesc = ((i & kk) == 0);
                    if (dirDesc ? !ib4l : ib4l) {
                        s_sc[i] = b; s_sc[l] = a;
                        s_ix[i] = bi; s_ix[l] = ai;
                    }
                }
            }
        }
    }
    __syncthreads();

    // ---- Phase 3: batched greedy NMS with early stop at MAXDET kept (wave 0 only) ----
    if (tid < 64) {
        const int lane = tid;
        int kc = 0;
        int base = 0;
        while (base < NBOX && kc < MAXDET) {
            int p = base + lane;
            float s = s_sc[p];
            int sidx = (int)s_ix[p];
            bool valid = s > SCORE_T;
            float4 b = *reinterpret_cast<const float4*>(boxes + sidx * 12);
            float x1 = b.x, y1 = b.y, x2 = b.z, y2 = b.w;
            float area = (x2 - x1) * (y2 - y1);

            // check against all kept-so-far boxes (broadcast LDS reads)
            bool sup = false;
            for (int k = 0; k < kc; ++k) {
                float iou = iou_fn(x1, y1, x2, y2, area,
                                   s_kx1[k], s_ky1[k], s_kx2[k], s_ky2[k], s_karea[k]);
                sup = sup || (iou > NMS_T);
            }
            bool alive = valid && !sup;

            // intra-batch greedy resolve (exact semantics: only finally-alive
            // earlier candidates suppress later ones)
            unsigned long long am = __ballot(alive);
            unsigned long long rem = am;
            while (rem) {
                int i = (int)__builtin_ctzll(rem);
                float bx1 = __shfl(x1, i), by1 = __shfl(y1, i);
                float bx2 = __shfl(x2, i), by2 = __shfl(y2, i);
                float ba  = __shfl(area, i);
                if (lane > i && alive) {
                    float iou = iou_fn(x1, y1, x2, y2, area, bx1, by1, bx2, by2, ba);
                    if (iou > NMS_T) alive = false;
                }
                am = __ballot(alive);
                rem = am & ~((2ull << i) - 1ull);  // bits strictly above i
            }

            // append survivors in order
            int rank = __popcll(am & ((1ull << lane) - 1ull));
            int slot = kc + rank;
            if (alive && slot < MAXDET) {
                s_kx1[slot] = x1; s_ky1[slot] = y1;
                s_kx2[slot] = x2; s_ky2[slot] = y2;
                s_karea[slot] = area; s_kscore[slot] = s;
                s_ksel[slot] = sidx;
            }
            kc += (int)__popcll(am);
            if (kc > MAXDET) kc = MAXDET;
            base += 64;
            // all scores after an invalid one are invalid (sorted desc) -> done
            if (__ballot(valid) != 0xFFFFFFFFFFFFFFFFull) break;
        }
        if (lane == 0) s_kc = kc;
    }
    __syncthreads();

    // ---- Phase 4: write 100 output slots ----
    if (tid < MAXDET) {
        const int kc = s_kc;
        float* ob = out;                 // (100,12)
        float* od = out + MAXDET * 12;   // (100,3)
        float* os = out + MAXDET * 15;   // (100,)
        float* ol = out + MAXDET * 16;   // (100,) labels
        float* oo = out + MAXDET * 17;   // (100,) orient
        if (tid < kc) {
            int sel = s_ksel[tid];
#pragma unroll
            for (int c = 0; c < 12; ++c) ob[tid * 12 + c] = boxes[sel * 12 + c];
            od[tid * 3 + 0] = dims[sel * 3 + 0];
            od[tid * 3 + 1] = dims[sel * 3 + 1];
            od[tid * 3 + 2] = dims[sel * 3 + 2];
            os[tid] = s_kscore[tid];
            ol[tid] = 0.0f;
            const float* c = cls + sel * 8;
            float m0 = fmaxf(c[0], c[4]);
            float m1 = fmaxf(c[1], c[5]);
            float m2 = fmaxf(c[2], c[6]);
            float m3 = fmaxf(c[3], c[7]);
            int o = 0; float best = m0;
            if (m1 > best) { best = m1; o = 1; }
            if (m2 > best) { best = m2; o = 2; }
            if (m3 > best) { best = m3; o = 3; }
            oo[tid] = (float)o;
        } else {
#pragma unroll
            for (int c = 0; c < 12; ++c) ob[tid * 12 + c] = -1.0f;
            od[tid * 3 + 0] = -1.0f; od[tid * 3 + 1] = -1.0f; od[tid * 3 + 2] = -1.0f;
            os[tid] = -1.0f; ol[tid] = -1.0f; oo[tid] = -1.0f;
        }
    }
}

extern "C" void kernel_launch(void* const* d_in, const int* in_sizes, int n_in,
                              void* d_out, int out_size, void* d_ws, size_t ws_size,
                              hipStream_t stream) {
    const float* boxes = (const float*)d_in[0];
    const float* dims  = (const float*)d_in[1];
    const float* cls   = (const float*)d_in[2];
    float* out = (float*)d_out;
    (void)in_sizes; (void)n_in; (void)out_size; (void)d_ws; (void)ws_size;
    filterdet_kernel<<<1, BT, 0, stream>>>(boxes, dims, cls, out);
}

// Round 2
// 61.308 us; speedup vs baseline: 3.1184x; 3.1184x over previous
//
#include <hip/hip_runtime.h>

#define NBOX 8192
#define BT 1024
#define MAXDET 100
#define SCORE_T 0.05f
#define NMS_T 0.5f
#define NBIN 2048
#define CAP 1024
#define KTGT 256

__device__ __forceinline__ float iou_fn(float x1, float y1, float x2, float y2, float area,
                                        float bx1, float by1, float bx2, float by2, float barea) {
    float iw = fminf(x2, bx2) - fmaxf(x1, bx1);
    float ih = fminf(y2, by2) - fmaxf(y1, by1);
    iw = fmaxf(iw, 0.0f);
    ih = fmaxf(ih, 0.0f);
    float inter = iw * ih;
    return inter / fmaxf(area + barea - inter, 1e-8f);
}

// Phase A (parallel across CUs): score -> monotonic uint key; 0 if invalid.
__global__ void score_key_kernel(const float* __restrict__ cls, unsigned* __restrict__ keys) {
    int i = blockIdx.x * blockDim.x + threadIdx.x;
    if (i < NBOX) {
        const float4 c0 = *reinterpret_cast<const float4*>(cls + i * 8);
        const float4 c1 = *reinterpret_cast<const float4*>(cls + i * 8 + 4);
        float s = fmaxf(fmaxf(fmaxf(c0.x, c1.x), fmaxf(c0.y, c1.y)),
                        fmaxf(fmaxf(c0.z, c1.z), fmaxf(c0.w, c1.w)));
        unsigned u = __float_as_uint(s);
        unsigned key = (u & 0x80000000u) ? ~u : (u | 0x80000000u);
        keys[i] = (s > SCORE_T) ? key : 0u;
    }
}

__global__ __launch_bounds__(BT) void nms_kernel(
    const float* __restrict__ boxes, const float* __restrict__ dims,
    const float* __restrict__ cls, const unsigned* __restrict__ keys,
    float* __restrict__ out) {
    __shared__ unsigned s_key[NBOX];          // 32KB
    __shared__ unsigned s_hA[NBIN];           // 8KB
    __shared__ unsigned s_hB[NBIN];           // 8KB
    __shared__ unsigned s_selk[CAP];          // 4KB
    __shared__ unsigned short s_seli[CAP];    // 2KB
    __shared__ float s_kx1[MAXDET], s_ky1[MAXDET], s_kx2[MAXDET], s_ky2[MAXDET];
    __shared__ float s_karea[MAXDET], s_kscore[MAXDET];
    __shared__ int s_ksel[MAXDET];
    __shared__ int s_kc;
    __shared__ int s_b1, s_b2;
    __shared__ unsigned s_above1, s_in1, s_in2;
    __shared__ int s_cnt;

    const int tid = threadIdx.x;

    for (int i = tid; i < NBOX; i += BT) s_key[i] = keys[i];
    if (tid == 0) s_kc = 0;

    unsigned ub = 0xFFFFFFFFu;  // exclusive upper bound on keys still unprocessed
    while (true) {
        // ---- L1 histogram on key bits [31:21] over {0 < key < ub} ----
        __syncthreads();
        for (int b = tid; b < NBIN; b += BT) s_hA[b] = 0u;
        __syncthreads();
        for (int j = 0; j < NBOX / BT; ++j) {
            unsigned k = s_key[tid + j * BT];
            if (k != 0u && k < ub) atomicAdd(&s_hA[k >> 21], 1u);
        }
        // suffix scan: sfx[b] = sum_{b' >= b} hist[b']
        unsigned* src = s_hA; unsigned* dst = s_hB;
        for (int d = 1; d < NBIN; d <<= 1) {
            __syncthreads();
            for (int b = tid; b < NBIN; b += BT)
                dst[b] = src[b] + ((b + d < NBIN) ? src[b + d] : 0u);
            unsigned* t = src; src = dst; dst = t;
        }
        __syncthreads();
        unsigned totalRem = src[0];
        if (totalRem == 0u) break;                     // no valid candidates left
        unsigned Kt = totalRem < KTGT ? totalRem : KTGT;
        for (int b = tid; b < NBIN; b += BT) {
            unsigned inc = src[b];
            unsigned abv = (b + 1 < NBIN) ? src[b + 1] : 0u;
            if (inc >= Kt && abv < Kt) { s_b1 = b; s_above1 = abv; s_in1 = inc; }
        }
        __syncthreads();
        const int B1 = s_b1;
        const unsigned above1 = s_above1;
        unsigned T, selCnt;
        if (s_in1 <= CAP) {
            // boundary bin fits entirely -> no refine needed (typical path)
            T = ((unsigned)B1) << 21;
            selCnt = s_in1;
        } else {
            // ---- L2 refine on bits [20:10] within bin B1 (rare) ----
            __syncthreads();
            for (int b = tid; b < NBIN; b += BT) s_hA[b] = 0u;
            __syncthreads();
            for (int j = 0; j < NBOX / BT; ++j) {
                unsigned k = s_key[tid + j * BT];
                if (k != 0u && k < ub && (k >> 21) == (unsigned)B1)
                    atomicAdd(&s_hA[(k >> 10) & (NBIN - 1)], 1u);
            }
            unsigned* src2 = s_hA; unsigned* dst2 = s_hB;
            for (int d = 1; d < NBIN; d <<= 1) {
                __syncthreads();
                for (int b = tid; b < NBIN; b += BT)
                    dst2[b] = src2[b] + ((b + d < NBIN) ? src2[b + d] : 0u);
                unsigned* t = src2; src2 = dst2; dst2 = t;
            }
            __syncthreads();
            unsigned Krem = Kt - above1;
            for (int b = tid; b < NBIN; b += BT) {
                unsigned inc = src2[b];
                unsigned abv = (b + 1 < NBIN) ? src2[b + 1] : 0u;
                if (inc >= Krem && abv < Krem) { s_b2 = b; s_in2 = inc; }
            }
            __syncthreads();
            T = (((unsigned)B1) << 21) | (((unsigned)s_b2) << 10);
            selCnt = above1 + s_in2;
            if (selCnt > CAP) selCnt = CAP;  // >CAP bit-identical keys: unreachable for this input
        }
        (void)selCnt;
        // ---- compact selected {T <= key < ub} ----
        if (tid == 0) s_cnt = 0;
        __syncthreads();
        for (int j = 0; j < NBOX / BT; ++j) {
            int i = tid + j * BT;
            unsigned k = s_key[i];
            if (k >= T && k < ub) {
                int pos = atomicAdd(&s_cnt, 1);
                if (pos < CAP) { s_selk[pos] = k; s_seli[pos] = (unsigned short)i; }
            }
        }
        __syncthreads();
        int sc = s_cnt; if (sc > CAP) sc = CAP;
        int n = 64; while (n < sc) n <<= 1;
        for (int i = sc + tid; i < n; i += BT) { s_selk[i] = 0u; s_seli[i] = 0; }
        // ---- bitonic sort [0,n) desc by (key desc, idx asc) ----
        for (int kk = 2; kk <= n; kk <<= 1) {
            for (int jj = kk >> 1; jj > 0; jj >>= 1) {
                __syncthreads();
                for (int i = tid; i < n; i += BT) {
                    int l = i ^ jj;
                    if (l > i) {
                        unsigned ka = s_selk[i], kb = s_selk[l];
                        unsigned short ia = s_seli[i], ibx = s_seli[l];
                        bool ib4l = (ka > kb) || (ka == kb && ia < ibx);
                        bool dirDesc = ((i & kk) == 0);
                        if (dirDesc ? !ib4l : ib4l) {
                            s_selk[i] = kb; s_selk[l] = ka;
                            s_seli[i] = ibx; s_seli[l] = ia;
                        }
                    }
                }
            }
        }
        __syncthreads();
        // ---- greedy NMS over sorted chunk (wave 0), exact semantics ----
        if (tid < 64) {
            const int lane = tid;
            int kc = s_kc;
            for (int base = 0; base < sc && kc < MAXDET; base += 64) {
                int p = base + lane;
                bool have = p < sc;
                int pp = have ? p : 0;
                unsigned key = s_selk[pp];
                int sidx = (int)s_seli[pp];
                float sscore = __uint_as_float(key & 0x7FFFFFFFu);  // valid keys are flipped positives
                float4 b = *reinterpret_cast<const float4*>(boxes + sidx * 12);
                float x1 = b.x, y1 = b.y, x2 = b.z, y2 = b.w;
                float area = (x2 - x1) * (y2 - y1);
                bool alive = have;
                for (int k = 0; k < kc; ++k) {
                    float iou = iou_fn(x1, y1, x2, y2, area,
                                       s_kx1[k], s_ky1[k], s_kx2[k], s_ky2[k], s_karea[k]);
                    alive = alive && !(iou > NMS_T);
                }
                // intra-batch greedy resolve
                unsigned long long am = __ballot(alive);
                unsigned long long rem = am;
                while (rem) {
                    int i = (int)__builtin_ctzll(rem);
                    float bx1 = __shfl(x1, i), by1 = __shfl(y1, i);
                    float bx2 = __shfl(x2, i), by2 = __shfl(y2, i);
                    float ba  = __shfl(area, i);
                    if (lane > i && alive) {
                        float iou = iou_fn(x1, y1, x2, y2, area, bx1, by1, bx2, by2, ba);
                        if (iou > NMS_T) alive = false;
                    }
                    am = __ballot(alive);
                    rem = am & ~((2ull << i) - 1ull);
                }
                int rank = (int)__popcll(am & ((1ull << lane) - 1ull));
                int slot = kc + rank;
                if (alive && slot < MAXDET) {
                    s_kx1[slot] = x1; s_ky1[slot] = y1;
                    s_kx2[slot] = x2; s_ky2[slot] = y2;
                    s_karea[slot] = area; s_kscore[slot] = sscore;
                    s_ksel[slot] = sidx;
                }
                kc += (int)__popcll(am);
                if (kc > MAXDET) kc = MAXDET;
            }
            if (lane == 0) s_kc = kc;
        }
        __syncthreads();
        if (s_kc >= MAXDET) break;
        ub = T;  // continue with next score band (rare)
    }
    __syncthreads();

    // ---- output: 100 slots ----
    if (tid < MAXDET) {
        const int kc = s_kc;
        float* ob = out;                 // (100,12)
        float* od = out + MAXDET * 12;   // (100,3)
        float* os = out + MAXDET * 15;   // (100,)
        float* ol = out + MAXDET * 16;   // (100,) labels
        float* oo = out + MAXDET * 17;   // (100,) orient
        if (tid < kc) {
            int sel = s_ksel[tid];
#pragma unroll
            for (int c = 0; c < 12; ++c) ob[tid * 12 + c] = boxes[sel * 12 + c];
            od[tid * 3 + 0] = dims[sel * 3 + 0];
            od[tid * 3 + 1] = dims[sel * 3 + 1];
            od[tid * 3 + 2] = dims[sel * 3 + 2];
            os[tid] = s_kscore[tid];
            ol[tid] = 0.0f;
            const float* c = cls + sel * 8;
            float m0 = fmaxf(c[0], c[4]);
            float m1 = fmaxf(c[1], c[5]);
            float m2 = fmaxf(c[2], c[6]);
            float m3 = fmaxf(c[3], c[7]);
            int o = 0; float best = m0;
            if (m1 > best) { best = m1; o = 1; }
            if (m2 > best) { best = m2; o = 2; }
            if (m3 > best) { best = m3; o = 3; }
            oo[tid] = (float)o;
        } else {
#pragma unroll
            for (int c = 0; c < 12; ++c) ob[tid * 12 + c] = -1.0f;
            od[tid * 3 + 0] = -1.0f; od[tid * 3 + 1] = -1.0f; od[tid * 3 + 2] = -1.0f;
            os[tid] = -1.0f; ol[tid] = -1.0f; oo[tid] = -1.0f;
        }
    }
}

extern "C" void kernel_launch(void* const* d_in, const int* in_sizes, int n_in,
                              void* d_out, int out_size, void* d_ws, size_t ws_size,
                              hipStream_t stream) {
    const float* boxes = (const float*)d_in[0];
    const float* dims  = (const float*)d_in[1];
    const float* cls   = (const float*)d_in[2];
    float* out = (float*)d_out;
    unsigned* keys = (unsigned*)d_ws;
    (void)in_sizes; (void)n_in; (void)out_size; (void)ws_size;
    score_key_kernel<<<NBOX / 256, 256, 0, stream>>>(cls, keys);
    nms_kernel<<<1, BT, 0, stream>>>(boxes, dims, cls, keys, out);
}

// Round 3
// 45.440 us; speedup vs baseline: 4.2074x; 1.3492x over previous
//
#include <hip/hip_runtime.h>

#define NBOX 8192
#define BT 1024
#define MAXDET 100
#define SCORE_T 0.05f
#define NMS_T 0.5f
#define CAP 1024
#define KTGT 256

__device__ __forceinline__ float iou_fn(float x1, float y1, float x2, float y2, float area,
                                        float bx1, float by1, float bx2, float by2, float barea) {
    float iw = fminf(x2, bx2) - fmaxf(x1, bx1);
    float ih = fminf(y2, by2) - fmaxf(y1, by1);
    iw = fmaxf(iw, 0.0f);
    ih = fmaxf(ih, 0.0f);
    float inter = iw * ih;
    return inter / fmaxf(area + barea - inter, 1e-8f);
}

__device__ __forceinline__ void bins_of(unsigned k, int& b1, int& b2) {
    float s = __uint_as_float(k & 0x7FFFFFFFu);
    b1 = (int)(s * 256.0f); if (b1 > 255) b1 = 255;
    b2 = (int)(s * 65536.0f) & 255;
}

__global__ __launch_bounds__(BT) void filterdet_kernel(
    const float* __restrict__ boxes, const float* __restrict__ dims,
    const float* __restrict__ cls, float* __restrict__ out) {
    __shared__ unsigned s_key[NBOX];              // 32KB
    __shared__ unsigned s_hist[256];
    __shared__ unsigned s_sfx[257];
    __shared__ unsigned long long s_sel[CAP];     // 8KB
    __shared__ unsigned long long s_srt[CAP];     // 8KB
    __shared__ float s_kx1[MAXDET], s_ky1[MAXDET], s_kx2[MAXDET], s_ky2[MAXDET];
    __shared__ float s_karea[MAXDET], s_kscore[MAXDET];
    __shared__ int s_ksel[MAXDET];
    __shared__ int s_kc, s_cnt, s_B1, s_B2;
    __shared__ unsigned s_in1, s_abv1;

    const int tid = threadIdx.x;
    const int lane = tid & 63;

    // ---- Phase 1: score -> monotonic key (0 = invalid) ----
    for (int i = tid; i < NBOX; i += BT) {
        const float4 c0 = *reinterpret_cast<const float4*>(cls + i * 8);
        const float4 c1 = *reinterpret_cast<const float4*>(cls + i * 8 + 4);
        float s = fmaxf(fmaxf(fmaxf(c0.x, c1.x), fmaxf(c0.y, c1.y)),
                        fmaxf(fmaxf(c0.z, c1.z), fmaxf(c0.w, c1.w)));
        unsigned u = __float_as_uint(s);
        unsigned key = (u >> 31) ? ~u : (u | 0x80000000u);
        s_key[i] = (s > SCORE_T) ? key : 0u;
    }
    if (tid == 0) s_kc = 0;

    int U1 = 256, U2 = 0;  // exclusive lexicographic upper bound (bin1,bin2)
    while (true) {
        // ---- histogram of in-range valid keys by value-uniform bin ----
        __syncthreads();
        if (tid < 256) s_hist[tid] = 0u;
        __syncthreads();
        for (int j = 0; j < NBOX / BT; ++j) {
            unsigned k = s_key[tid + j * BT];
            if (k) {
                int b1, b2; bins_of(k, b1, b2);
                if (b1 < U1 || (b1 == U1 && b2 < U2)) atomicAdd(&s_hist[b1], 1u);
            }
        }
        __syncthreads();
        // ---- wave-0 suffix scan over 256 bins ----
        if (tid < 64) {
            unsigned c0 = s_hist[lane * 4 + 0], c1 = s_hist[lane * 4 + 1];
            unsigned c2 = s_hist[lane * 4 + 2], c3 = s_hist[lane * 4 + 3];
            unsigned t3 = c3, t2 = c2 + t3, t1 = c1 + t2, t0 = c0 + t1;
            unsigned acc = t0;
#pragma unroll
            for (int d = 1; d < 64; d <<= 1) {
                unsigned o = __shfl_down(acc, d);
                if (lane + d < 64) acc += o;
            }
            unsigned excl = acc - t0;
            s_sfx[lane * 4 + 0] = excl + t0;
            s_sfx[lane * 4 + 1] = excl + t1;
            s_sfx[lane * 4 + 2] = excl + t2;
            s_sfx[lane * 4 + 3] = excl + t3;
            if (lane == 0) s_sfx[256] = 0u;
        }
        __syncthreads();
        unsigned totalRem = s_sfx[0];
        if (totalRem == 0u) break;
        unsigned Kt = totalRem < KTGT ? totalRem : KTGT;
        if (tid < 256) {
            unsigned inc = s_sfx[tid], abv = s_sfx[tid + 1];
            if (inc >= Kt && abv < Kt) { s_B1 = tid; s_in1 = inc - abv; s_abv1 = abv; s_B2 = 0; }
        }
        __syncthreads();
        const int B1 = s_B1;
        int B2 = 0;
        if (s_abv1 + s_in1 > CAP) {
            // ---- refine within bin B1 (unreachable for this input, kept for exactness) ----
            __syncthreads();
            if (tid < 256) s_hist[tid] = 0u;
            __syncthreads();
            for (int j = 0; j < NBOX / BT; ++j) {
                unsigned k = s_key[tid + j * BT];
                if (k) {
                    int b1, b2; bins_of(k, b1, b2);
                    if ((b1 < U1 || (b1 == U1 && b2 < U2)) && b1 == B1)
                        atomicAdd(&s_hist[b2], 1u);
                }
            }
            __syncthreads();
            if (tid < 64) {
                unsigned c0 = s_hist[lane * 4 + 0], c1 = s_hist[lane * 4 + 1];
                unsigned c2 = s_hist[lane * 4 + 2], c3 = s_hist[lane * 4 + 3];
                unsigned t3 = c3, t2 = c2 + t3, t1 = c1 + t2, t0 = c0 + t1;
                unsigned acc = t0;
#pragma unroll
                for (int d = 1; d < 64; d <<= 1) {
                    unsigned o = __shfl_down(acc, d);
                    if (lane + d < 64) acc += o;
                }
                unsigned excl = acc - t0;
                s_sfx[lane * 4 + 0] = excl + t0;
                s_sfx[lane * 4 + 1] = excl + t1;
                s_sfx[lane * 4 + 2] = excl + t2;
                s_sfx[lane * 4 + 3] = excl + t3;
                if (lane == 0) s_sfx[256] = 0u;
            }
            __syncthreads();
            unsigned Krem = Kt - s_abv1;
            if (tid < 256) {
                unsigned inc = s_sfx[tid], abv = s_sfx[tid + 1];
                if (inc >= Krem && abv < Krem) s_B2 = tid;
            }
            __syncthreads();
            B2 = s_B2;
        }
        // ---- compact band [B, U) into packed u64 (key desc, idx asc) ----
        if (tid == 0) s_cnt = 0;
        __syncthreads();
        for (int j = 0; j < NBOX / BT; ++j) {
            int i = tid + j * BT;
            unsigned k = s_key[i];
            if (k) {
                int b1, b2; bins_of(k, b1, b2);
                bool inr = (b1 < U1) || (b1 == U1 && b2 < U2);
                bool sel = inr && ((b1 > B1) || (b1 == B1 && b2 >= B2));
                if (sel) {
                    int pos = atomicAdd(&s_cnt, 1);
                    if (pos < CAP)
                        s_sel[pos] = (((unsigned long long)k) << 13) | (unsigned)(NBOX - 1 - i);
                }
            }
        }
        __syncthreads();
        const int sc = s_cnt < CAP ? s_cnt : CAP;
        // ---- rank-sort (keys all distinct; broadcast LDS reads) ----
        for (int t = tid; t < sc; t += BT) {
            unsigned long long mine = s_sel[t];
            int rank = 0;
            for (int j = 0; j < sc; ++j) rank += (s_sel[j] > mine) ? 1 : 0;
            s_srt[rank] = mine;
        }
        __syncthreads();
        // ---- greedy NMS over sorted band (wave 0), exact semantics ----
        if (tid < 64) {
            int kc = s_kc;
            for (int base = 0; base < sc && kc < MAXDET; base += 64) {
                int p = base + lane;
                bool have = p < sc;
                unsigned long long v = have ? s_srt[p] : 0ull;
                unsigned key = (unsigned)(v >> 13);
                int sidx = NBOX - 1 - (int)(v & 8191ull);
                float sscore = __uint_as_float(key & 0x7FFFFFFFu);
                float4 b = *reinterpret_cast<const float4*>(boxes + sidx * 12);
                float x1 = b.x, y1 = b.y, x2 = b.z, y2 = b.w;
                float area = (x2 - x1) * (y2 - y1);
                bool alive = have;
                for (int k = 0; k < kc; ++k) {
                    float iou = iou_fn(x1, y1, x2, y2, area,
                                       s_kx1[k], s_ky1[k], s_kx2[k], s_ky2[k], s_karea[k]);
                    alive = alive && !(iou > NMS_T);
                }
                unsigned long long am = __ballot(alive);
                unsigned long long rem = am;
                while (rem) {
                    int i = (int)__builtin_ctzll(rem);
                    float bx1 = __shfl(x1, i), by1 = __shfl(y1, i);
                    float bx2 = __shfl(x2, i), by2 = __shfl(y2, i);
                    float ba  = __shfl(area, i);
                    if (lane > i && alive) {
                        float iou = iou_fn(x1, y1, x2, y2, area, bx1, by1, bx2, by2, ba);
                        if (iou > NMS_T) alive = false;
                    }
                    am = __ballot(alive);
                    rem = am & ~((2ull << i) - 1ull);
                }
                int rank = (int)__popcll(am & ((1ull << lane) - 1ull));
                int slot = kc + rank;
                if (alive && slot < MAXDET) {
                    s_kx1[slot] = x1; s_ky1[slot] = y1;
                    s_kx2[slot] = x2; s_ky2[slot] = y2;
                    s_karea[slot] = area; s_kscore[slot] = sscore;
                    s_ksel[slot] = sidx;
                }
                kc += (int)__popcll(am);
                if (kc > MAXDET) kc = MAXDET;
            }
            if (lane == 0) s_kc = kc;
        }
        __syncthreads();
        if (s_kc >= MAXDET) break;
        U1 = B1; U2 = B2;  // strict lexicographic progress
    }
    __syncthreads();

    // ---- output: 100 slots ----
    if (tid < MAXDET) {
        const int kc = s_kc;
        float* ob = out;                 // (100,12)
        float* od = out + MAXDET * 12;   // (100,3)
        float* os = out + MAXDET * 15;   // (100,)
        float* ol = out + MAXDET * 16;   // (100,) labels
        float* oo = out + MAXDET * 17;   // (100,) orient
        if (tid < kc) {
            int sel = s_ksel[tid];
#pragma unroll
            for (int c = 0; c < 12; ++c) ob[tid * 12 + c] = boxes[sel * 12 + c];
            od[tid * 3 + 0] = dims[sel * 3 + 0];
            od[tid * 3 + 1] = dims[sel * 3 + 1];
            od[tid * 3 + 2] = dims[sel * 3 + 2];
            os[tid] = s_kscore[tid];
            ol[tid] = 0.0f;
            const float* c = cls + sel * 8;
            float m0 = fmaxf(c[0], c[4]);
            float m1 = fmaxf(c[1], c[5]);
            float m2 = fmaxf(c[2], c[6]);
            float m3 = fmaxf(c[3], c[7]);
            int o = 0; float best = m0;
            if (m1 > best) { best = m1; o = 1; }
            if (m2 > best) { best = m2; o = 2; }
            if (m3 > best) { best = m3; o = 3; }
            oo[tid] = (float)o;
        } else {
#pragma unroll
            for (int c = 0; c < 12; ++c) ob[tid * 12 + c] = -1.0f;
            od[tid * 3 + 0] = -1.0f; od[tid * 3 + 1] = -1.0f; od[tid * 3 + 2] = -1.0f;
            os[tid] = -1.0f; ol[tid] = -1.0f; oo[tid] = -1.0f;
        }
    }
}

extern "C" void kernel_launch(void* const* d_in, const int* in_sizes, int n_in,
                              void* d_out, int out_size, void* d_ws, size_t ws_size,
                              hipStream_t stream) {
    const float* boxes = (const float*)d_in[0];
    const float* dims  = (const float*)d_in[1];
    const float* cls   = (const float*)d_in[2];
    float* out = (float*)d_out;
    (void)in_sizes; (void)n_in; (void)out_size; (void)d_ws; (void)ws_size;
    filterdet_kernel<<<1, BT, 0, stream>>>(boxes, dims, cls, out);
}

// Round 4
// 33.491 us; speedup vs baseline: 5.7085x; 1.3568x over previous
//
#include <hip/hip_runtime.h>

#define NBOX 8192
#define BT 1024
#define MAXDET 100
#define SCORE_T 0.05f
#define NMS_T 0.5f
#define CAP 1024
#define KTGT 128

__device__ __forceinline__ float iou_fn(float x1, float y1, float x2, float y2, float area,
                                        float bx1, float by1, float bx2, float by2, float barea) {
    float iw = fminf(x2, bx2) - fmaxf(x1, bx1);
    float ih = fminf(y2, by2) - fmaxf(y1, by1);
    iw = fmaxf(iw, 0.0f);
    ih = fmaxf(ih, 0.0f);
    float inter = iw * ih;
    return inter / fmaxf(area + barea - inter, 1e-8f);
}

__device__ __forceinline__ void bins_of(unsigned k, int& b1, int& b2) {
    float s = __uint_as_float(k & 0x7FFFFFFFu);
    b1 = (int)(s * 256.0f); if (b1 > 255) b1 = 255;
    b2 = (int)(s * 65536.0f) & 255;
}

__global__ __launch_bounds__(BT) void filterdet_kernel(
    const float* __restrict__ boxes, const float* __restrict__ dims,
    const float* __restrict__ cls, float* __restrict__ out) {
    __shared__ unsigned s_key[NBOX];              // 32KB
    __shared__ unsigned s_hist[256];
    __shared__ unsigned s_sfx[257];
    __shared__ unsigned long long s_sel[CAP];     // 8KB
    __shared__ unsigned long long s_srt[CAP];     // 8KB
    __shared__ unsigned short s_srtpos[CAP];      // 2KB
    __shared__ float4 s_cb[CAP];                  // 16KB candidate boxes
    __shared__ float s_kx1[MAXDET], s_ky1[MAXDET], s_kx2[MAXDET], s_ky2[MAXDET];
    __shared__ float s_karea[MAXDET], s_kscore[MAXDET];
    __shared__ int s_ksel[MAXDET];
    __shared__ float s_bx1[64], s_by1[64], s_bx2[64], s_by2[64], s_bar[64];
    __shared__ int s_kc, s_cnt, s_B1, s_B2;
    __shared__ unsigned s_in1, s_abv1;

    const int tid = threadIdx.x;
    const int lane = tid & 63;

    // ---- Phase 1: score -> monotonic key (0 = invalid); overlap hist clear ----
#pragma unroll
    for (int j = 0; j < NBOX / BT; ++j) {
        int i = tid + j * BT;
        const float4 c0 = *reinterpret_cast<const float4*>(cls + i * 8);
        const float4 c1 = *reinterpret_cast<const float4*>(cls + i * 8 + 4);
        float s = fmaxf(fmaxf(fmaxf(c0.x, c1.x), fmaxf(c0.y, c1.y)),
                        fmaxf(fmaxf(c0.z, c1.z), fmaxf(c0.w, c1.w)));
        unsigned u = __float_as_uint(s);
        unsigned key = (u >> 31) ? ~u : (u | 0x80000000u);
        s_key[i] = (s > SCORE_T) ? key : 0u;
    }
    if (tid < 256) s_hist[tid] = 0u;
    if (tid == 0) s_kc = 0;

    int U1 = 256, U2 = 0;  // exclusive lexicographic upper bound (bin1,bin2)
    while (true) {
        __syncthreads();   // keys ready, hist cleared
        // ---- histogram of in-range valid keys ----
        for (int j = 0; j < NBOX / BT; ++j) {
            unsigned k = s_key[tid + j * BT];
            if (k) {
                int b1, b2; bins_of(k, b1, b2);
                if (b1 < U1 || (b1 == U1 && b2 < U2)) atomicAdd(&s_hist[b1], 1u);
            }
        }
        __syncthreads();
        // ---- wave-0 suffix scan over 256 bins ----
        if (tid < 64) {
            unsigned c0 = s_hist[lane * 4 + 0], c1 = s_hist[lane * 4 + 1];
            unsigned c2 = s_hist[lane * 4 + 2], c3 = s_hist[lane * 4 + 3];
            unsigned t3 = c3, t2 = c2 + t3, t1 = c1 + t2, t0 = c0 + t1;
            unsigned acc = t0;
#pragma unroll
            for (int d = 1; d < 64; d <<= 1) {
                unsigned o = __shfl_down(acc, d);
                if (lane + d < 64) acc += o;
            }
            unsigned excl = acc - t0;
            s_sfx[lane * 4 + 0] = excl + t0;
            s_sfx[lane * 4 + 1] = excl + t1;
            s_sfx[lane * 4 + 2] = excl + t2;
            s_sfx[lane * 4 + 3] = excl + t3;
            if (lane == 0) s_sfx[256] = 0u;
        }
        __syncthreads();
        unsigned totalRem = s_sfx[0];
        if (totalRem == 0u) break;
        unsigned Kt = totalRem < KTGT ? totalRem : KTGT;
        if (tid < 256) {
            unsigned inc = s_sfx[tid], abv = s_sfx[tid + 1];
            if (inc >= Kt && abv < Kt) { s_B1 = tid; s_in1 = inc - abv; s_abv1 = abv; s_B2 = 0; }
        }
        if (tid == 0) s_cnt = 0;
        __syncthreads();
        const int B1 = s_B1;
        int B2 = 0;
        if (s_abv1 + s_in1 > CAP) {
            // ---- refine within bin B1 (kept for exactness; unreachable here) ----
            __syncthreads();
            if (tid < 256) s_hist[tid] = 0u;
            __syncthreads();
            for (int j = 0; j < NBOX / BT; ++j) {
                unsigned k = s_key[tid + j * BT];
                if (k) {
                    int b1, b2; bins_of(k, b1, b2);
                    if ((b1 < U1 || (b1 == U1 && b2 < U2)) && b1 == B1)
                        atomicAdd(&s_hist[b2], 1u);
                }
            }
            __syncthreads();
            if (tid < 64) {
                unsigned c0 = s_hist[lane * 4 + 0], c1 = s_hist[lane * 4 + 1];
                unsigned c2 = s_hist[lane * 4 + 2], c3 = s_hist[lane * 4 + 3];
                unsigned t3 = c3, t2 = c2 + t3, t1 = c1 + t2, t0 = c0 + t1;
                unsigned acc = t0;
#pragma unroll
                for (int d = 1; d < 64; d <<= 1) {
                    unsigned o = __shfl_down(acc, d);
                    if (lane + d < 64) acc += o;
                }
                unsigned excl = acc - t0;
                s_sfx[lane * 4 + 0] = excl + t0;
                s_sfx[lane * 4 + 1] = excl + t1;
                s_sfx[lane * 4 + 2] = excl + t2;
                s_sfx[lane * 4 + 3] = excl + t3;
                if (lane == 0) s_sfx[256] = 0u;
            }
            __syncthreads();
            unsigned Krem = Kt - s_abv1;
            if (tid < 256) {
                unsigned inc = s_sfx[tid], abv = s_sfx[tid + 1];
                if (inc >= Krem && abv < Krem) s_B2 = tid;
            }
            __syncthreads();
            B2 = s_B2;
        }
        // ---- compact band into packed u64 (key desc, idx asc via inverted idx) ----
        for (int j = 0; j < NBOX / BT; ++j) {
            int i = tid + j * BT;
            unsigned k = s_key[i];
            if (k) {
                int b1, b2; bins_of(k, b1, b2);
                bool inr = (b1 < U1) || (b1 == U1 && b2 < U2);
                bool sel = inr && ((b1 > B1) || (b1 == B1 && b2 >= B2));
                if (sel) {
                    int pos = atomicAdd(&s_cnt, 1);
                    if (pos < CAP)
                        s_sel[pos] = (((unsigned long long)k) << 13) | (unsigned)(NBOX - 1 - i);
                }
            }
        }
        __syncthreads();
        const int sc = s_cnt < CAP ? s_cnt : CAP;
        // ---- prefetch candidate boxes (issue loads early, store after sort) ----
        bool hasEl = tid < sc;
        float4 preb = make_float4(0.f, 0.f, 0.f, 0.f);
        unsigned long long mine = 0ull;
        if (hasEl) {
            mine = s_sel[tid];
            int bidx = NBOX - 1 - (int)(mine & 8191ull);
            preb = *reinterpret_cast<const float4*>(boxes + bidx * 12);
        }
        // ---- rank-sort (keys all distinct; broadcast LDS reads) ----
        if (hasEl) {
            int rank = 0;
            for (int j = 0; j < sc; ++j) rank += (s_sel[j] > mine) ? 1 : 0;
            s_srt[rank] = mine;
            s_srtpos[rank] = (unsigned short)tid;
            s_cb[tid] = preb;
        }
        __syncthreads();
        // ---- greedy NMS over sorted band (wave 0), exact semantics ----
        if (tid < 64) {
            int kc = s_kc;
            for (int base = 0; base < sc && kc < MAXDET; base += 64) {
                int p = base + lane;
                bool have = p < sc;
                unsigned long long v = have ? s_srt[p] : 0ull;
                int cp = have ? (int)s_srtpos[p] : 0;
                unsigned key = (unsigned)(v >> 13);
                int sidx = NBOX - 1 - (int)(v & 8191ull);
                float sscore = __uint_as_float(key & 0x7FFFFFFFu);
                float4 b = s_cb[cp];
                float x1 = b.x, y1 = b.y, x2 = b.z, y2 = b.w;
                float area = (x2 - x1) * (y2 - y1);
                // stage batch for pairwise mask (wave-synchronous LDS exchange)
                s_bx1[lane] = x1; s_by1[lane] = y1;
                s_bx2[lane] = x2; s_by2[lane] = y2; s_bar[lane] = area;
                // check vs all previously-kept boxes
                bool cand = have;
                for (int k = 0; k < kc; ++k) {
                    float iou = iou_fn(x1, y1, x2, y2, area,
                                       s_kx1[k], s_ky1[k], s_kx2[k], s_ky2[k], s_karea[k]);
                    cand = cand && !(iou > NMS_T);
                }
                // intra-batch suppressor bitmask (strictly lower lanes only)
                unsigned long long m = 0ull;
#pragma unroll 4
                for (int j = 0; j < 64; ++j) {
                    float iou = iou_fn(x1, y1, x2, y2, area,
                                       s_bx1[j], s_by1[j], s_bx2[j], s_by2[j], s_bar[j]);
                    if ((iou > NMS_T) && (j < lane)) m |= (1ull << j);
                }
                // greedy resolve over conflicted lanes only (~1-2 iterations)
                unsigned long long alive = __ballot(cand);
                unsigned long long conf = __ballot((m & alive) != 0ull) & alive;
                while (conf) {
                    int i = (int)__builtin_ctzll(conf);
                    bool deadI = (lane == i) && ((m & alive) != 0ull);
                    unsigned long long d = __ballot(deadI);
                    alive &= ~d;
                    conf &= ~(d | (1ull << i));
                }
                int rank = (int)__popcll(alive & ((1ull << lane) - 1ull));
                int slot = kc + rank;
                if (((alive >> lane) & 1ull) && slot < MAXDET) {
                    s_kx1[slot] = x1; s_ky1[slot] = y1;
                    s_kx2[slot] = x2; s_ky2[slot] = y2;
                    s_karea[slot] = area; s_kscore[slot] = sscore;
                    s_ksel[slot] = sidx;
                }
                kc += (int)__popcll(alive);
                if (kc > MAXDET) kc = MAXDET;
            }
            if (lane == 0) s_kc = kc;
        }
        __syncthreads();
        if (s_kc >= MAXDET) break;
        U1 = B1; U2 = B2;  // strict lexicographic progress
        __syncthreads();
        if (tid < 256) s_hist[tid] = 0u;   // re-clear for next band
    }
    __syncthreads();

    // ---- output: 100 slots ----
    if (tid < MAXDET) {
        const int kc = s_kc;
        float* ob = out;                 // (100,12)
        float* od = out + MAXDET * 12;   // (100,3)
        float* os = out + MAXDET * 15;   // (100,)
        float* ol = out + MAXDET * 16;   // (100,) labels
        float* oo = out + MAXDET * 17;   // (100,) orient
        if (tid < kc) {
            int sel = s_ksel[tid];
#pragma unroll
            for (int c = 0; c < 12; ++c) ob[tid * 12 + c] = boxes[sel * 12 + c];
            od[tid * 3 + 0] = dims[sel * 3 + 0];
            od[tid * 3 + 1] = dims[sel * 3 + 1];
            od[tid * 3 + 2] = dims[sel * 3 + 2];
            os[tid] = s_kscore[tid];
            ol[tid] = 0.0f;
            const float* c = cls + sel * 8;
            float m0 = fmaxf(c[0], c[4]);
            float m1 = fmaxf(c[1], c[5]);
            float m2 = fmaxf(c[2], c[6]);
            float m3 = fmaxf(c[3], c[7]);
            int o = 0; float best = m0;
            if (m1 > best) { best = m1; o = 1; }
            if (m2 > best) { best = m2; o = 2; }
            if (m3 > best) { best = m3; o = 3; }
            oo[tid] = (float)o;
        } else {
#pragma unroll
            for (int c = 0; c < 12; ++c) ob[tid * 12 + c] = -1.0f;
            od[tid * 3 + 0] = -1.0f; od[tid * 3 + 1] = -1.0f; od[tid * 3 + 2] = -1.0f;
            os[tid] = -1.0f; ol[tid] = -1.0f; oo[tid] = -1.0f;
        }
    }
}

extern "C" void kernel_launch(void* const* d_in, const int* in_sizes, int n_in,
                              void* d_out, int out_size, void* d_ws, size_t ws_size,
                              hipStream_t stream) {
    const float* boxes = (const float*)d_in[0];
    const float* dims  = (const float*)d_in[1];
    const float* cls   = (const float*)d_in[2];
    float* out = (float*)d_out;
    (void)in_sizes; (void)n_in; (void)out_size; (void)d_ws; (void)ws_size;
    filterdet_kernel<<<1, BT, 0, stream>>>(boxes, dims, cls, out);
}